// Round 1
// baseline (834.834 us; speedup 1.0000x reference)
//
#include <hip/hip_runtime.h>
#include <hip/hip_bf16.h>
#include <stdint.h>

typedef __attribute__((ext_vector_type(8))) short bf16x8;
typedef __attribute__((ext_vector_type(4))) float f32x4;
typedef __attribute__((ext_vector_type(8))) unsigned short u16x8;

#define TILE 128
#define BK 32

// Exact replication of reference mxfp8_quant_dequant for one element, given the
// block exponent e = floor(log2(amax)) - 8.
// xs = x / 2^e (exact); clip to +-448; RNE to e4m3 grid (software, v_rndne);
// result * 2^e. Output is exactly representable in bf16 (<=4 significand bits).
__device__ __forceinline__ float mx_qd_elem(float x, int e) {
    float xs = ldexpf(x, -e);
    xs = fminf(448.f, fmaxf(-448.f, xs));
    float a = fabsf(xs);
    float r;
    if (a < 0.015625f) {                  // below 2^-6: e4m3 subnormal, quantum 2^-9
        r = ldexpf(rintf(ldexpf(a, 9)), -9);
    } else {                              // normal: quantum 2^(E-3)
        int E = (int)((__float_as_uint(a) >> 23) & 0xFF) - 127;
        r = ldexpf(rintf(ldexpf(a, 3 - E)), E - 3);
    }
    r = copysignf(r, xs);
    return ldexpf(r, e);
}

// One thread = one MX block of 32 contiguous fp32 along K. Writes bf16 (as u16).
__global__ __launch_bounds__(256) void mx_quant_bf16(
    const float* __restrict__ in, uint16_t* __restrict__ out, int nblk) {
    int t = blockIdx.x * 256 + threadIdx.x;
    if (t >= nblk) return;
    const float4* p = (const float4*)(in + (size_t)t * 32);
    float v[32];
#pragma unroll
    for (int i = 0; i < 8; ++i) {
        float4 f = p[i];
        v[4 * i + 0] = f.x; v[4 * i + 1] = f.y;
        v[4 * i + 2] = f.z; v[4 * i + 3] = f.w;
    }
    float amax = 0.f;
#pragma unroll
    for (int i = 0; i < 32; ++i) amax = fmaxf(amax, fabsf(v[i]));
    amax = fmaxf(amax, 1.17549435e-38f);                   // 2^-126 clamp (ref)
    int e = (int)((__float_as_uint(amax) >> 23) & 0xFF) - 127 - 8;  // floor(log2)-8, exact

    unsigned short res[32];
#pragma unroll
    for (int i = 0; i < 32; ++i) {
        float d = mx_qd_elem(v[i], e);
        res[i] = (unsigned short)(__float_as_uint(d) >> 16);  // exact bf16 (value fits)
    }
    u16x8* o = (u16x8*)(out + (size_t)t * 32);
#pragma unroll
    for (int j = 0; j < 4; ++j) {
        u16x8 pack;
#pragma unroll
        for (int i = 0; i < 8; ++i) pack[i] = res[8 * j + i];
        o[j] = pack;
    }
}

// C = A * B^T + bias.  A:[Nrows,K] bf16, B:[O,K] bf16 (both K-major), C:[Nrows,O] f32.
// m97 structure: 128x128 tile, BK=32, 4 waves (2x2), 16x16x32 bf16 MFMA, 4x4 frags/wave,
// global_load_lds width-16 staging, 2 barriers per K-step.
__global__ __launch_bounds__(256) void mx_gemm_bf16(
    const uint16_t* __restrict__ A, const uint16_t* __restrict__ B,
    const float* __restrict__ bias, float* __restrict__ C,
    int Nrows, int K, int O) {
    __shared__ __align__(16) uint16_t sA[TILE * BK];
    __shared__ __align__(16) uint16_t sB[TILE * BK];

    const int tid  = threadIdx.x;
    const int lane = tid & 63;
    const int w    = tid >> 6;
    const int wr   = w >> 1, wc = w & 1;
    const int rowBase = blockIdx.y * TILE;
    const int colBase = blockIdx.x * TILE;

    const int lr = lane & 15;            // fragment row (A) / col (B)
    const int lk = (lane >> 4) << 3;     // k offset within K=32 step

    f32x4 acc[4][4];
#pragma unroll
    for (int m = 0; m < 4; ++m)
#pragma unroll
        for (int n = 0; n < 4; ++n)
#pragma unroll
            for (int j = 0; j < 4; ++j) acc[m][n][j] = 0.f;

    // staging geometry: 8 chunks of 1024B per matrix; chunk ci = w*2+c;
    // linear elem = ci*512 + lane*8 ; row = elem>>5 ; col = elem&31
    for (int k0 = 0; k0 < K; k0 += BK) {
        __syncthreads();   // previous compute done before LDS overwrite
#pragma unroll
        for (int c = 0; c < 2; ++c) {
            int ci   = w * 2 + c;
            int elem = ci * 512 + lane * 8;
            int row  = elem >> 5;
            int col  = elem & 31;
            const uint16_t* ga = A + (size_t)(rowBase + row) * K + k0 + col;
            const uint16_t* gb = B + (size_t)(colBase + row) * K + k0 + col;
            __builtin_amdgcn_global_load_lds(
                (__attribute__((address_space(1))) void*)ga,
                (__attribute__((address_space(3))) void*)&sA[ci * 512], 16, 0, 0);
            __builtin_amdgcn_global_load_lds(
                (__attribute__((address_space(1))) void*)gb,
                (__attribute__((address_space(3))) void*)&sB[ci * 512], 16, 0, 0);
        }
        __syncthreads();   // compiler drains vmcnt(0) before barrier

        bf16x8 af[4], bfr[4];
#pragma unroll
        for (int m = 0; m < 4; ++m)
            af[m] = *(const bf16x8*)&sA[(wr * 64 + m * 16 + lr) * BK + lk];
#pragma unroll
        for (int n = 0; n < 4; ++n)
            bfr[n] = *(const bf16x8*)&sB[(wc * 64 + n * 16 + lr) * BK + lk];
#pragma unroll
        for (int m = 0; m < 4; ++m)
#pragma unroll
            for (int n = 0; n < 4; ++n)
                acc[m][n] = __builtin_amdgcn_mfma_f32_16x16x32_bf16(
                    af[m], bfr[n], acc[m][n], 0, 0, 0);
    }

    // epilogue: C/D layout col=lane&15, row=(lane>>4)*4+j  (m89/m91)
    const int qr = (lane >> 4) * 4;
#pragma unroll
    for (int n = 0; n < 4; ++n) {
        int col = colBase + wc * 64 + n * 16 + lr;
        float bv = bias[col];
#pragma unroll
        for (int m = 0; m < 4; ++m) {
            int r0 = rowBase + wr * 64 + m * 16 + qr;
#pragma unroll
            for (int j = 0; j < 4; ++j)
                C[(size_t)(r0 + j) * O + col] = acc[m][n][j] + bv;
        }
    }
}

extern "C" void kernel_launch(void* const* d_in, const int* in_sizes, int n_in,
                              void* d_out, int out_size, void* d_ws, size_t ws_size,
                              hipStream_t stream) {
    const float* x    = (const float*)d_in[0];
    const float* wgt  = (const float*)d_in[1];
    const float* bias = (const float*)d_in[2];
    float* out = (float*)d_out;

    const int D_OUT = in_sizes[2];             // 4096
    const int D_IN  = in_sizes[1] / D_OUT;     // 4096
    const int NROWS = in_sizes[0] / D_IN;      // 16384

    uint16_t* xq = (uint16_t*)d_ws;                     // NROWS*D_IN bf16 = 128 MB
    uint16_t* wq = xq + (size_t)NROWS * D_IN;           // D_OUT*D_IN bf16 =  32 MB

    int nblkx = NROWS * (D_IN / 32);
    int nblkw = D_OUT * (D_IN / 32);
    mx_quant_bf16<<<dim3((nblkx + 255) / 256), dim3(256), 0, stream>>>(x, xq, nblkx);
    mx_quant_bf16<<<dim3((nblkw + 255) / 256), dim3(256), 0, stream>>>(wgt, wq, nblkw);

    dim3 grid(D_OUT / TILE, NROWS / TILE);   // (32, 128)
    mx_gemm_bf16<<<grid, dim3(256), 0, stream>>>(xq, wq, bias, out, NROWS, D_IN, D_OUT);
}

// Round 5
// 723.527 us; speedup vs baseline: 1.1538x; 1.1538x over previous
//
#include <hip/hip_runtime.h>
#include <hip/hip_bf16.h>
#include <stdint.h>

typedef __attribute__((ext_vector_type(8))) short bf16x8;
typedef __attribute__((ext_vector_type(4))) float f32x4;
typedef __attribute__((ext_vector_type(8))) unsigned short u16x8;

#define BM 256
#define BN 128
#define BKT 64
#define ABYTES (BM * BKT * 2)        // 32768
#define BBYTES (BN * BKT * 2)        // 16384
#define BUFBYTES (ABYTES + BBYTES)   // 49152
#define NBUF 3                       // 144 KB LDS ring

// ---- MXFP8 quant-dequant to bf16 (verified round 1: absmax 0.03125) --------
__device__ __forceinline__ float mx_qd_elem(float x, int e) {
    float xs = ldexpf(x, -e);
    xs = fminf(448.f, fmaxf(-448.f, xs));
    float a = fabsf(xs);
    float r;
    if (a < 0.015625f) {                  // below 2^-6: e4m3 subnormal, quantum 2^-9
        r = ldexpf(rintf(ldexpf(a, 9)), -9);
    } else {                              // normal: quantum 2^(E-3)
        int E = (int)((__float_as_uint(a) >> 23) & 0xFF) - 127;
        r = ldexpf(rintf(ldexpf(a, 3 - E)), E - 3);
    }
    r = copysignf(r, xs);
    return ldexpf(r, e);
}

__global__ __launch_bounds__(256) void mx_quant_bf16(
    const float* __restrict__ in, uint16_t* __restrict__ out, int nblk) {
    int t = blockIdx.x * 256 + threadIdx.x;
    if (t >= nblk) return;
    const float4* p = (const float4*)(in + (size_t)t * 32);
    float v[32];
#pragma unroll
    for (int i = 0; i < 8; ++i) {
        float4 fv = p[i];
        v[4 * i + 0] = fv.x; v[4 * i + 1] = fv.y;
        v[4 * i + 2] = fv.z; v[4 * i + 3] = fv.w;
    }
    float amax = 0.f;
#pragma unroll
    for (int i = 0; i < 32; ++i) amax = fmaxf(amax, fabsf(v[i]));
    amax = fmaxf(amax, 1.17549435e-38f);
    int e = (int)((__float_as_uint(amax) >> 23) & 0xFF) - 127 - 8;

    unsigned short res[32];
#pragma unroll
    for (int i = 0; i < 32; ++i) {
        float d = mx_qd_elem(v[i], e);
        res[i] = (unsigned short)(__float_as_uint(d) >> 16);
    }
    u16x8* o = (u16x8*)(out + (size_t)t * 32);
#pragma unroll
    for (int j = 0; j < 4; ++j) {
        u16x8 pack;
#pragma unroll
        for (int i = 0; i < 8; ++i) pack[i] = res[8 * j + i];
        o[j] = pack;
    }
}

// ---- deep-pipelined bf16 GEMM: C = A * B^T + bias --------------------------
// 256x128 tile, BK=64, 8 waves (4M x 2N, 64x64 each), 3-buffer LDS ring,
// depth-2 K-tile prefetch with counted vmcnt(6), T2 XOR-swizzle, T5 setprio.
#define GLOAD(srcp, ldsoff)                                                     \
    __builtin_amdgcn_global_load_lds(                                           \
        (const __attribute__((address_space(1))) void*)(srcp),                  \
        (__attribute__((address_space(3))) void*)&lds[ldsoff], 16, 0, 0)

__global__ __launch_bounds__(512, 2) void gemm_pipe_bf16(
    const uint16_t* __restrict__ A, const uint16_t* __restrict__ B,
    const float* __restrict__ bias, float* __restrict__ C,
    int Nrows, int K, int O) {
    __shared__ __align__(16) uint8_t lds[NBUF * BUFBYTES];   // 144 KB

    const int tid  = threadIdx.x;
    const int lane = tid & 63;
    const int w    = tid >> 6;
    const int f    = lane & 15, g = lane >> 4;
    const int wm   = w >> 1,    wn = w & 1;

    // T1: bijective XCD swizzle (nwg = 2048, %8 == 0)
    const int nwg  = gridDim.x * gridDim.y;
    const int flat = blockIdx.y * gridDim.x + blockIdx.x;
    const int swz  = (flat & 7) * (nwg >> 3) + (flat >> 3);
    const int bx   = swz % gridDim.x, by = swz / gridDim.x;
    const int rowBase = by * BM, colBase = bx * BN;

    // staging geometry: each wave's gload covers 1024 B = 8 rows x 128 B.
    // linear LDS dest (rule 21); SOURCE col pre-inverse-swizzled.
    const int rl   = lane >> 3;                              // row in 8-row chunk
    const int scol = ((lane & 7) * 16) ^ ((rl & 7) << 4);    // byte col in source
    const uint8_t* gA = (const uint8_t*)A;
    const uint8_t* gB = (const uint8_t*)B;
    const size_t K2 = (size_t)K * 2;

    // swizzled frag-read offsets: LDS[r][c] = G[r][c ^ ((r&7)<<4)]
    int aoff[4][2], boff[4][2];
#pragma unroll
    for (int kk = 0; kk < 2; ++kk) {
        int colb = (kk * 64 + g * 16) ^ ((f & 7) << 4);
#pragma unroll
        for (int m = 0; m < 4; ++m)
            aoff[m][kk] = (wm * 64 + m * 16 + f) * 128 + colb;
#pragma unroll
        for (int n = 0; n < 4; ++n)
            boff[n][kk] = ABYTES + (wn * 64 + n * 16 + f) * 128 + colb;
    }

    f32x4 acc[4][4];
#pragma unroll
    for (int m = 0; m < 4; ++m)
#pragma unroll
        for (int n = 0; n < 4; ++n)
#pragma unroll
            for (int j = 0; j < 4; ++j) acc[m][n][j] = 0.f;

    const int nt = K / BKT;   // 64

#define STAGE_A(t, li) do {                                                     \
        int _buf = (t) % NBUF;                                                  \
        int _row = (li) * 64 + w * 8 + rl;                                      \
        GLOAD(gA + (size_t)(rowBase + _row) * K2 + (size_t)(t) * (BKT*2) + scol,\
              _buf * BUFBYTES + (li) * 8192 + w * 1024);                        \
    } while (0)
#define STAGE_B(t, li) do {                                                     \
        int _buf = (t) % NBUF;                                                  \
        int _row = (li) * 64 + w * 8 + rl;                                      \
        GLOAD(gB + (size_t)(colBase + _row) * K2 + (size_t)(t) * (BKT*2) + scol,\
              _buf * BUFBYTES + ABYTES + (li) * 8192 + w * 1024);               \
    } while (0)

    // prologue: stage tiles 0 and 1 (6 loads each)
    STAGE_A(0, 0); STAGE_A(0, 1); STAGE_A(0, 2); STAGE_A(0, 3);
    STAGE_B(0, 0); STAGE_B(0, 1);
    STAGE_A(1, 0); STAGE_A(1, 1); STAGE_A(1, 2); STAGE_A(1, 3);
    STAGE_B(1, 0); STAGE_B(1, 1);
    asm volatile("s_waitcnt vmcnt(6)" ::: "memory");   // tile 0 landed, tile 1 flying
    __builtin_amdgcn_sched_barrier(0);
    __builtin_amdgcn_s_barrier();
    __builtin_amdgcn_sched_barrier(0);

    for (int t = 0; t < nt; ++t) {
        if (t > 0) {
            // publish tile t; keep tile t+1's 6 loads in flight (counted, not 0)
            if (t == nt - 1) asm volatile("s_waitcnt vmcnt(0)" ::: "memory");
            else             asm volatile("s_waitcnt vmcnt(6)" ::: "memory");
            __builtin_amdgcn_sched_barrier(0);
            __builtin_amdgcn_s_barrier();
            __builtin_amdgcn_sched_barrier(0);
        }
        const int base = (t % NBUF) * BUFBYTES;
        const bool pf = (t + 2) < nt;   // stage target buf (t+2)%3 = (t-1)%3: free
        bf16x8 bfr[4];
#pragma unroll
        for (int p = 0; p < 4; ++p) {
            const int kk = p >> 1, mh = p & 1;
            if (pf) {
                if (p == 0) { STAGE_A(t + 2, 0); STAGE_A(t + 2, 1); }
                if (p == 1) { STAGE_A(t + 2, 2); STAGE_A(t + 2, 3); }
                if (p == 2) { STAGE_B(t + 2, 0); STAGE_B(t + 2, 1); }
            }
            if (mh == 0) {
#pragma unroll
                for (int n = 0; n < 4; ++n)
                    bfr[n] = *(const bf16x8*)&lds[base + boff[n][kk]];
            }
            bf16x8 af0 = *(const bf16x8*)&lds[base + aoff[mh * 2 + 0][kk]];
            bf16x8 af1 = *(const bf16x8*)&lds[base + aoff[mh * 2 + 1][kk]];
            __builtin_amdgcn_s_setprio(1);
#pragma unroll
            for (int n = 0; n < 4; ++n) {
                acc[mh * 2 + 0][n] = __builtin_amdgcn_mfma_f32_16x16x32_bf16(
                    af0, bfr[n], acc[mh * 2 + 0][n], 0, 0, 0);
                acc[mh * 2 + 1][n] = __builtin_amdgcn_mfma_f32_16x16x32_bf16(
                    af1, bfr[n], acc[mh * 2 + 1][n], 0, 0, 0);
            }
            __builtin_amdgcn_s_setprio(0);
            __builtin_amdgcn_s_barrier();
            __builtin_amdgcn_sched_barrier(0);
        }
    }

    // epilogue: C/D layout col=lane&15, row=(lane>>4)*4+j (m89, r1-verified)
    const int qr = g * 4;
#pragma unroll
    for (int n = 0; n < 4; ++n) {
        int col = colBase + wn * 64 + n * 16 + f;
        float bv = bias[col];
#pragma unroll
        for (int m = 0; m < 4; ++m) {
            int r0 = rowBase + wm * 64 + m * 16 + qr;
#pragma unroll
            for (int j = 0; j < 4; ++j)
                C[(size_t)(r0 + j) * O + col] = acc[m][n][j] + bv;
        }
    }
#undef STAGE_A
#undef STAGE_B
}

extern "C" void kernel_launch(void* const* d_in, const int* in_sizes, int n_in,
                              void* d_out, int out_size, void* d_ws, size_t ws_size,
                              hipStream_t stream) {
    const float* x    = (const float*)d_in[0];
    const float* wgt  = (const float*)d_in[1];
    const float* bias = (const float*)d_in[2];
    float* out = (float*)d_out;

    const int D_OUT = in_sizes[2];             // 4096
    const int D_IN  = in_sizes[1] / D_OUT;     // 4096
    const int NROWS = in_sizes[0] / D_IN;      // 16384

    uint16_t* xq = (uint16_t*)d_ws;                     // 128 MB
    uint16_t* wq = xq + (size_t)NROWS * D_IN;           //  32 MB

    int nblkx = NROWS * (D_IN / 32);
    int nblkw = D_OUT * (D_IN / 32);
    mx_quant_bf16<<<dim3((nblkx + 255) / 256), dim3(256), 0, stream>>>(x, xq, nblkx);
    mx_quant_bf16<<<dim3((nblkw + 255) / 256), dim3(256), 0, stream>>>(wgt, wq, nblkw);

    dim3 grid(D_OUT / BN, NROWS / BM);   // (32, 64) = 2048 blocks
    gemm_pipe_bf16<<<grid, dim3(512), 0, stream>>>(xq, wq, bias, out,
                                                   NROWS, D_IN, D_OUT);
}

// Round 6
// 607.403 us; speedup vs baseline: 1.3744x; 1.1912x over previous
//
#include <hip/hip_runtime.h>
#include <hip/hip_bf16.h>
#include <stdint.h>

typedef __attribute__((ext_vector_type(8))) short bf16x8;
typedef __attribute__((ext_vector_type(4))) float f32x4;
typedef __attribute__((ext_vector_type(8))) unsigned short u16x8;

#define BM 256
#define BN 256
#define BKT 64
#define ABYTES (BM * BKT * 2)        // 32768
#define BBYTES (BN * BKT * 2)        // 32768
#define BUFBYTES (ABYTES + BBYTES)   // 65536
// 2 buffers = 128 KB LDS

// ---- MXFP8 quant-dequant to bf16 (verified r1/r5: absmax 0.03125) ----------
__device__ __forceinline__ float mx_qd_elem(float x, int e) {
    float xs = ldexpf(x, -e);
    xs = fminf(448.f, fmaxf(-448.f, xs));
    float a = fabsf(xs);
    float r;
    if (a < 0.015625f) {                  // below 2^-6: e4m3 subnormal, quantum 2^-9
        r = ldexpf(rintf(ldexpf(a, 9)), -9);
    } else {                              // normal: quantum 2^(E-3)
        int E = (int)((__float_as_uint(a) >> 23) & 0xFF) - 127;
        r = ldexpf(rintf(ldexpf(a, 3 - E)), E - 3);
    }
    r = copysignf(r, xs);
    return ldexpf(r, e);
}

__global__ __launch_bounds__(256) void mx_quant_bf16(
    const float* __restrict__ in, uint16_t* __restrict__ out, int nblk) {
    int t = blockIdx.x * 256 + threadIdx.x;
    if (t >= nblk) return;
    const float4* p = (const float4*)(in + (size_t)t * 32);
    float v[32];
#pragma unroll
    for (int i = 0; i < 8; ++i) {
        float4 fv = p[i];
        v[4 * i + 0] = fv.x; v[4 * i + 1] = fv.y;
        v[4 * i + 2] = fv.z; v[4 * i + 3] = fv.w;
    }
    float amax = 0.f;
#pragma unroll
    for (int i = 0; i < 32; ++i) amax = fmaxf(amax, fabsf(v[i]));
    amax = fmaxf(amax, 1.17549435e-38f);
    int e = (int)((__float_as_uint(amax) >> 23) & 0xFF) - 127 - 8;

    unsigned short res[32];
#pragma unroll
    for (int i = 0; i < 32; ++i) {
        float d = mx_qd_elem(v[i], e);
        res[i] = (unsigned short)(__float_as_uint(d) >> 16);
    }
    u16x8* o = (u16x8*)(out + (size_t)t * 32);
#pragma unroll
    for (int j = 0; j < 4; ++j) {
        u16x8 pack;
#pragma unroll
        for (int i = 0; i < 8; ++i) pack[i] = res[8 * j + i];
        o[j] = pack;
    }
}

// ---- 256x256 minimal-2-phase bf16 GEMM: C = A * B^T + bias -----------------
// 8 waves (2M x 4N), per-wave 128x64 (acc[8][4]); BK=64; 2-buf LDS (128 KB);
// stage(t+1) at iter top -> compute t -> vmcnt(0)+barrier (1 barrier/K-tile);
// T2 XOR-swizzle (r5-verified, 0 conflicts); T1 XCD swizzle; T5 setprio.
#define GLOAD(srcp, ldsoff)                                                     \
    __builtin_amdgcn_global_load_lds(                                           \
        (const __attribute__((address_space(1))) void*)(srcp),                  \
        (__attribute__((address_space(3))) void*)&lds[ldsoff], 16, 0, 0)

__global__ __launch_bounds__(512, 2) void gemm_256_bf16(
    const uint16_t* __restrict__ A, const uint16_t* __restrict__ B,
    const float* __restrict__ bias, float* __restrict__ C,
    int Nrows, int K, int O) {
    __shared__ __align__(16) uint8_t lds[2 * BUFBYTES];   // 128 KB

    const int tid  = threadIdx.x;
    const int lane = tid & 63;
    const int w    = tid >> 6;
    const int f    = lane & 15, g = lane >> 4;
    const int wm   = w >> 2,    wn = w & 3;     // 2M x 4N

    // T1: bijective XCD swizzle (nwg = 1024, %8 == 0)
    const int nwg  = gridDim.x * gridDim.y;
    const int flat = blockIdx.y * gridDim.x + blockIdx.x;
    const int swz  = (flat & 7) * (nwg >> 3) + (flat >> 3);
    const int bx   = swz % gridDim.x, by = swz / gridDim.x;
    const int rowBase = by * BM, colBase = bx * BN;

    // staging: call i covers 64 rows (8 KB); wave writes 1 KB linear LDS.
    // source col pre-inverse-swizzled (rule 21; r5-verified formulas).
    const int rl   = lane >> 3;                              // 0..7
    const int scol = ((lane & 7) * 16) ^ (rl << 4);
    const uint8_t* gA = (const uint8_t*)A;
    const uint8_t* gB = (const uint8_t*)B;
    const size_t K2 = (size_t)K * 2;

    // swizzled frag-read offsets: LDS[r][c] = G[r][c ^ ((r&7)<<4)], 16B units
    int aoff[8][2], boff[4][2];
#pragma unroll
    for (int kk = 0; kk < 2; ++kk) {
        const int colb = (kk * 64 + g * 16) ^ ((f & 7) << 4);
#pragma unroll
        for (int m = 0; m < 8; ++m)
            aoff[m][kk] = (wm * 128 + m * 16 + f) * 128 + colb;
#pragma unroll
        for (int n = 0; n < 4; ++n)
            boff[n][kk] = ABYTES + (wn * 64 + n * 16 + f) * 128 + colb;
    }

    f32x4 acc[8][4];
#pragma unroll
    for (int m = 0; m < 8; ++m)
#pragma unroll
        for (int n = 0; n < 4; ++n)
#pragma unroll
            for (int j = 0; j < 4; ++j) acc[m][n][j] = 0.f;

    const int nt = K / BKT;   // 64

#define STAGE(t) do {                                                           \
        const int _buf = ((t) & 1) * BUFBYTES;                                  \
        const size_t _kb = (size_t)(t) * (BKT * 2);                             \
        _Pragma("unroll")                                                       \
        for (int _i = 0; _i < 4; ++_i)                                          \
            GLOAD(gA + (size_t)(rowBase + _i * 64 + w * 8 + rl) * K2 + _kb + scol, \
                  _buf + _i * 8192 + w * 1024);                                 \
        _Pragma("unroll")                                                       \
        for (int _i = 0; _i < 4; ++_i)                                          \
            GLOAD(gB + (size_t)(colBase + _i * 64 + w * 8 + rl) * K2 + _kb + scol, \
                  _buf + ABYTES + _i * 8192 + w * 1024);                        \
    } while (0)

    // prologue: stage tile 0, wait, publish
    STAGE(0);
    asm volatile("s_waitcnt vmcnt(0)" ::: "memory");
    __builtin_amdgcn_sched_barrier(0);
    __builtin_amdgcn_s_barrier();
    __builtin_amdgcn_sched_barrier(0);

    for (int t = 0; t < nt; ++t) {
        if (t + 1 < nt) STAGE(t + 1);          // into buf (t+1)&1 (freed by barrier)
        const int base = (t & 1) * BUFBYTES;

        bf16x8 bfr[4][2];
#pragma unroll
        for (int n = 0; n < 4; ++n) {
            bfr[n][0] = *(const bf16x8*)&lds[base + boff[n][0]];
            bfr[n][1] = *(const bf16x8*)&lds[base + boff[n][1]];
        }
#pragma unroll
        for (int m = 0; m < 8; ++m) {
            bf16x8 a0 = *(const bf16x8*)&lds[base + aoff[m][0]];
            bf16x8 a1 = *(const bf16x8*)&lds[base + aoff[m][1]];
            __builtin_amdgcn_s_setprio(1);
#pragma unroll
            for (int n = 0; n < 4; ++n) {
                acc[m][n] = __builtin_amdgcn_mfma_f32_16x16x32_bf16(
                    a0, bfr[n][0], acc[m][n], 0, 0, 0);
                acc[m][n] = __builtin_amdgcn_mfma_f32_16x16x32_bf16(
                    a1, bfr[n][1], acc[m][n], 0, 0, 0);
            }
            __builtin_amdgcn_s_setprio(0);
        }
        // publish: tile t+1 landed (issued ~2500 cyc ago) + all waves done
        // reading buf t (their lgkm reads drained before their MFMAs).
        asm volatile("s_waitcnt vmcnt(0)" ::: "memory");
        __builtin_amdgcn_sched_barrier(0);
        __builtin_amdgcn_s_barrier();
        __builtin_amdgcn_sched_barrier(0);
    }
#undef STAGE

    // epilogue: C/D layout col=lane&15, row=(lane>>4)*4+j (r1/r5-verified)
    const int qr = g * 4;
#pragma unroll
    for (int n = 0; n < 4; ++n) {
        int col = colBase + wn * 64 + n * 16 + f;
        float bv = bias[col];
#pragma unroll
        for (int m = 0; m < 8; ++m) {
            int r0 = rowBase + wm * 128 + m * 16 + qr;
#pragma unroll
            for (int j = 0; j < 4; ++j)
                C[(size_t)(r0 + j) * O + col] = acc[m][n][j] + bv;
        }
    }
}

extern "C" void kernel_launch(void* const* d_in, const int* in_sizes, int n_in,
                              void* d_out, int out_size, void* d_ws, size_t ws_size,
                              hipStream_t stream) {
    const float* x    = (const float*)d_in[0];
    const float* wgt  = (const float*)d_in[1];
    const float* bias = (const float*)d_in[2];
    float* out = (float*)d_out;

    const int D_OUT = in_sizes[2];             // 4096
    const int D_IN  = in_sizes[1] / D_OUT;     // 4096
    const int NROWS = in_sizes[0] / D_IN;      // 16384

    uint16_t* xq = (uint16_t*)d_ws;                     // 128 MB
    uint16_t* wq = xq + (size_t)NROWS * D_IN;           //  32 MB

    int nblkx = NROWS * (D_IN / 32);
    int nblkw = D_OUT * (D_IN / 32);
    mx_quant_bf16<<<dim3((nblkx + 255) / 256), dim3(256), 0, stream>>>(x, xq, nblkx);
    mx_quant_bf16<<<dim3((nblkw + 255) / 256), dim3(256), 0, stream>>>(wgt, wq, nblkw);

    dim3 grid(D_OUT / BN, NROWS / BM);   // (16, 64) = 1024 blocks
    gemm_256_bf16<<<grid, dim3(512), 0, stream>>>(xq, wq, bias, out,
                                                  NROWS, D_IN, D_OUT);
}